// Round 3
// baseline (278.853 us; speedup 1.0000x reference)
//
#include <hip/hip_runtime.h>
#include <math.h>
#include <stdint.h>

#define NPART 16384
#define NSTEP 40
#define DIMA  22
#define OUT0_ELEMS 13434880
#define TRAJ_OFF   160

typedef __attribute__((ext_vector_type(8))) short short8;
typedef __attribute__((ext_vector_type(4))) float floatx4;
typedef __attribute__((ext_vector_type(4))) int   intx4;
typedef __attribute__((ext_vector_type(2))) int   intx2;

union V4 { intx4 i; short8 s; floatx4 f; };

// ---- LDS map (bytes): permuted-weight image (staging only; weights live in
// registers/AGPRs during the main loop) ----
#define AIN_B   0
#define AH_B    5120
#define AOUT_B  56320
#define U_B     61440
#define LDS_BYTES 62080
#define STAGE_DW  15360

// HW packed f32->bf16 (RNE), single instruction.
__device__ __forceinline__ uint32_t pk2(float a0, float a1) {
    uint32_t r;
    asm("v_cvt_pk_bf16_f32 %0, %1, %2" : "=v"(r) : "v"(a0), "v"(a1));
    return r;
}
__device__ __forceinline__ float fast_tanh(float x) {
    float e = __expf(2.0f * x);
    return 1.0f - 2.0f * __builtin_amdgcn_rcpf(e + 1.0f);
}

__global__ __launch_bounds__(256, 1) void sde_mfma(
    const float* __restrict__ z,      const float* __restrict__ t_arr,
    const float* __restrict__ Tx,     const float* __restrict__ noise,
    const float* __restrict__ dw_in,  const float* __restrict__ db_in,
    const float* __restrict__ dw_h,   const float* __restrict__ db_h,
    const float* __restrict__ dw_out, const float* __restrict__ db_out,
    const float* __restrict__ tw_in,  const float* __restrict__ tb_in,
    const float* __restrict__ tw_h,   const float* __restrict__ tb_h,
    const float* __restrict__ tw_out, const float* __restrict__ tb_out,
    float* __restrict__ out0,         float* __restrict__ traj)
{
    __shared__ __align__(16) uint8_t lds[LDS_BYTES];
    const int tid = threadIdx.x;

    // ---- stage PERMUTED bf16 weight image global -> LDS ----
    //   A'[m][32kt+8q+2w+jj] = A[m][16(2kt+(w>>1)) + 4q + 2(w&1) + jj]
    // Input-layer bias folded at B-slot (q=2, w=2); B[k=20]=1.0 injected by
    // quad==2 lanes each step.
    for (int di = tid; di < STAGE_DW; di += 256) {
        uint32_t val = 0u;
        if (di < 1280) {                       // AIN: x = [y(20), u_t(4), bias@k20]
            int r = di & 255, lane = r >> 2, w = r & 3;
            int m = lane & 15, q = lane >> 4, mt = di >> 8;
            int f = -1;
            if (w < 2)            f = 4 * q + 2 * w;
            else if (q == 0)      f = 16 + 2 * (w - 2);
            else if (q == 1)      f = 20 + 2 * (w - 2);
            if (f >= 0)               val = pk2(dw_in[(mt * 16 + m) * 24 + f],
                                                dw_in[(mt * 16 + m) * 24 + f + 1]);
            else if (q == 2 && w == 2) val = pk2(db_in[mt * 16 + m], 0.f);
        } else if (di < 14080) {               // AH: 20 groups x 640 dw
            int q2 = di - 1280, g = q2 / 640, r = q2 % 640;
            int l = g / 5, mt = g % 5;
            int lane, f;
            if (r < 512) {
                int kt = r >> 8, rr = r & 255, w = rr & 3;
                lane = rr >> 2;
                f = 16 * (2 * kt + (w >> 1)) + 4 * (lane >> 4) + 2 * (w & 1);
            } else {
                int rr = r - 512, d = rr & 1;
                lane = rr >> 1;
                f = 64 + 4 * (lane >> 4) + 2 * d;
            }
            int m = lane & 15;
            val = pk2(dw_h[l * 6400 + (mt * 16 + m) * 80 + f],
                      dw_h[l * 6400 + (mt * 16 + m) * 80 + f + 1]);
        } else {                               // AOUT: 2 groups x 640 dw
            int q2 = di - 14080, mt = q2 / 640, r = q2 % 640;
            int lane, f;
            if (r < 512) {
                int kt = r >> 8, rr = r & 255, w = rr & 3;
                lane = rr >> 2;
                f = 16 * (2 * kt + (w >> 1)) + 4 * (lane >> 4) + 2 * (w & 1);
            } else {
                int rr = r - 512, d = rr & 1;
                lane = rr >> 1;
                f = 64 + 4 * (lane >> 4) + 2 * d;
            }
            int m = mt * 16 + (lane & 15);
            if (m < 20) val = pk2(dw_out[m * 80 + f], dw_out[m * 80 + f + 1]);
        }
        ((uint32_t*)lds)[di] = val;
    }
    if (tid < NSTEP) {   // t-MLP u(t_i), fp32
        float ti = t_arr[tid];
        float hh[20], h2[20];
        #pragma unroll
        for (int j = 0; j < 20; j++) {
            float v = tw_in[j] * ti + tb_in[j];
            hh[j] = v > 0.f ? v : 0.f;
        }
        #pragma unroll
        for (int l = 0; l < 4; l++) {
            #pragma unroll
            for (int j = 0; j < 20; j++) {
                float a = tb_h[l * 20 + j];
                #pragma unroll
                for (int k = 0; k < 20; k++) a += tw_h[(l * 20 + j) * 20 + k] * hh[k];
                h2[j] = a > 0.f ? a : 0.f;
            }
            #pragma unroll
            for (int j = 0; j < 20; j++) hh[j] = h2[j];
        }
        #pragma unroll
        for (int c = 0; c < 4; c++) {
            float a = tb_out[c];
            #pragma unroll
            for (int k = 0; k < 20; k++) a += tw_out[c * 20 + k] * hh[k];
            ((float*)(lds + U_B))[tid * 4 + c] = a;
        }
    }

    const int lane = tid & 63;
    const int n15  = lane & 15;
    const int quad = lane >> 4;
    const int wv   = tid >> 6;
    const int n    = blockIdx.x * 64 + wv * 16 + n15;
    const float Txb = Tx[blockIdx.x];
    const float dtv = t_arr[1] - t_arr[0];
    const float sdt = sqrtf(dtv);
    const float hsdt = 0.5f * sdt;

    __syncthreads();

    // ---- hoist ALL weight A-fragments LDS -> registers (one-time) ----
    // Hidden/output bias folded into a2 dword2 (B-slot q=0, w=2 carries 1.0).
    V4 aIn[5];
    #pragma unroll
    for (int mt = 0; mt < 5; mt++)
        aIn[mt].i = *(const intx4*)(lds + AIN_B + mt * 1024 + lane * 16);

    V4 aH0[20], aH1[20], aH2[20];
    #pragma unroll
    for (int l = 0; l < 4; l++) {
        #pragma unroll
        for (int mt = 0; mt < 5; mt++) {
            const int g = l * 5 + mt;
            const uint8_t* grp = lds + AH_B + (size_t)g * 2560;
            aH0[g].i = *(const intx4*)(grp + lane * 16);
            aH1[g].i = *(const intx4*)(grp + 1024 + lane * 16);
            intx2 h2 = *(const intx2*)(grp + 2048 + lane * 8);
            uint32_t bd = (quad == 0) ? pk2(db_h[l * 80 + mt * 16 + n15], 0.f) : 0u;
            aH2[g].i = (intx4){h2[0], h2[1], (int)bd, 0};
        }
    }

    V4 aO0[2], aO1[2], aO2[2];
    #pragma unroll
    for (int mt = 0; mt < 2; mt++) {
        const uint8_t* grp = lds + AOUT_B + (size_t)mt * 2560;
        aO0[mt].i = *(const intx4*)(grp + lane * 16);
        aO1[mt].i = *(const intx4*)(grp + 1024 + lane * 16);
        intx2 h2 = *(const intx2*)(grp + 2048 + lane * 8);
        int m = mt * 16 + n15;
        uint32_t bd = (quad == 0 && m < 20) ? pk2(db_out[m], 0.f) : 0u;
        aO2[mt].i = (intx4){h2[0], h2[1], (int)bd, 0};
    }

    const floatx4 zf = {0.f, 0.f, 0.f, 0.f};

    // state in D-layout: y0[r] = y[quad*4+r]; y1[r] = y[16+quad*4+r] (quad0)
    float y0[4], y1[4] = {0.f, 0.f, 0.f, 0.f};
    {
        floatx4 zv = *(const floatx4*)(z + (size_t)n * 20 + quad * 4);
        #pragma unroll
        for (int r = 0; r < 4; r++) y0[r] = zv[r];
        *(floatx4*)(out0 + (size_t)n * 20 + quad * 4) = zv;
        if (quad == 0) {
            floatx4 z2 = *(const floatx4*)(z + (size_t)n * 20 + 16);
            #pragma unroll
            for (int r = 0; r < 4; r++) y1[r] = z2[r];
            *(floatx4*)(out0 + (size_t)n * 20 + 16) = z2;
            traj[n] = 0.f;
        }
    }

    // ---- software prefetch pipelines: noise (global) and u-table (LDS) ----
    floatx4 dW0n = *(const floatx4*)(noise + ((size_t)0 * NPART + n) * DIMA + quad * 4);
    floatx4 dW1n = *(const floatx4*)(noise + ((size_t)0 * NPART + n) * DIMA + 16);
    floatx4 uvn  = *(const floatx4*)((const float*)(lds + U_B));

    float lq = 0.f;
    for (int i = 0; i < NSTEP; i++) {
        // consume prefetched values (loads issued a full step ago -> no stall)
        floatx4 dW0 = dW0n, dW1 = dW1n, uv = uvn;
        if (i + 1 < NSTEP) {
            size_t nb2 = ((size_t)(i + 1) * NPART + n) * DIMA;
            dW0n = *(const floatx4*)(noise + nb2 + quad * 4);
            dW1n = *(const floatx4*)(noise + nb2 + 16);
            uvn  = *(const floatx4*)((const float*)(lds + U_B) + (i + 1) * 4);
        }

        float ut0 = uv[0] * Txb, ut1 = uv[1] * Txb;
        float ut2 = uv[2] * Txb, ut3 = uv[3] * Txb;

        // ---- input B-frag: direct register pack; quad2 injects bias 1.0@k20 ----
        V4 bin;
        bin.i[0] = pk2(y0[0], y0[1]);
        bin.i[1] = pk2(y0[2], y0[3]);
        if (quad == 0)      { bin.i[2] = pk2(y1[0], y1[1]); bin.i[3] = pk2(y1[2], y1[3]); }
        else if (quad == 1) { bin.i[2] = pk2(ut0, ut1);     bin.i[3] = pk2(ut2, ut3); }
        else if (quad == 2) { bin.i[2] = 0x00003F80;        bin.i[3] = 0; }
        else                { bin.i[2] = 0;                 bin.i[3] = 0; }

        // ---- input layer: relu(W_in' x + b), bias via MFMA ----
        floatx4 acc[5];
        #pragma unroll
        for (int mt = 0; mt < 5; mt++)
            acc[mt] = __builtin_amdgcn_mfma_f32_16x16x32_bf16(aIn[mt].s, bin.s, zf, 0, 0, 0);
        uint32_t pkA[5][2];
        #pragma unroll
        for (int mt = 0; mt < 5; mt++) {
            pkA[mt][0] = pk2(fmaxf(acc[mt][0], 0.f), fmaxf(acc[mt][1], 0.f));
            pkA[mt][1] = pk2(fmaxf(acc[mt][2], 0.f), fmaxf(acc[mt][3], 0.f));
        }

        // ---- 4 hidden tanh layers: parallel partial accumulators ----
        #pragma unroll
        for (int l = 0; l < 4; l++) {
            V4 b0, b1, b2;
            b0.i = (intx4){(int)pkA[0][0], (int)pkA[0][1], (int)pkA[1][0], (int)pkA[1][1]};
            b1.i = (intx4){(int)pkA[2][0], (int)pkA[2][1], (int)pkA[3][0], (int)pkA[3][1]};
            b2.i = (intx4){(int)pkA[4][0], (int)pkA[4][1], 0x00003F80, 0};
            #pragma unroll
            for (int mt = 0; mt < 5; mt++) {
                const int g = l * 5 + mt;
                floatx4 c0 = __builtin_amdgcn_mfma_f32_16x16x32_bf16(aH0[g].s, b0.s, zf, 0, 0, 0);
                floatx4 c1 = __builtin_amdgcn_mfma_f32_16x16x32_bf16(aH1[g].s, b1.s, zf, 0, 0, 0);
                floatx4 c2 = __builtin_amdgcn_mfma_f32_16x16x32_bf16(aH2[g].s, b2.s, zf, 0, 0, 0);
                acc[mt] = (c0 + c1) + c2;
            }
            #pragma unroll
            for (int mt = 0; mt < 5; mt++) {
                pkA[mt][0] = pk2(fast_tanh(acc[mt][0]), fast_tanh(acc[mt][1]));
                pkA[mt][1] = pk2(fast_tanh(acc[mt][2]), fast_tanh(acc[mt][3]));
            }
        }

        // ---- output layer (M=20 padded to 32), parallel accumulators ----
        V4 b0, b1, b2;
        b0.i = (intx4){(int)pkA[0][0], (int)pkA[0][1], (int)pkA[1][0], (int)pkA[1][1]};
        b1.i = (intx4){(int)pkA[2][0], (int)pkA[2][1], (int)pkA[3][0], (int)pkA[3][1]};
        b2.i = (intx4){(int)pkA[4][0], (int)pkA[4][1], 0x00003F80, 0};
        floatx4 oacc[2];
        #pragma unroll
        for (int mt = 0; mt < 2; mt++) {
            floatx4 c0 = __builtin_amdgcn_mfma_f32_16x16x32_bf16(aO0[mt].s, b0.s, zf, 0, 0, 0);
            floatx4 c1 = __builtin_amdgcn_mfma_f32_16x16x32_bf16(aO1[mt].s, b1.s, zf, 0, 0, 0);
            floatx4 c2 = __builtin_amdgcn_mfma_f32_16x16x32_bf16(aO2[mt].s, b2.s, zf, 0, 0, 0);
            oacc[mt] = (c0 + c1) + c2;
        }

        // ---- SDE update + logqp ----
        float part = 0.f;
        size_t obase = ((size_t)(i + 1) * NPART + n) * 20;
        floatx4 st;
        #pragma unroll
        for (int r = 0; r < 4; r++) {
            float o = oacc[0][r];
            float y = y0[r];
            float f = o + y;                 // f = mlp - h, h = -y
            float uu = 2.f * o + 4.f * y;    // (f - h)/sigma
            part += uu * uu;
            y0[r] = y + f * dtv + hsdt * dW0[r];
            st[r] = y0[r];
        }
        *(floatx4*)(out0 + obase + quad * 4) = st;
        if (quad == 0) {
            floatx4 st2;
            #pragma unroll
            for (int r = 0; r < 4; r++) {
                float o = oacc[1][r];
                float y = y1[r];
                float f = o + y;
                float uu = 2.f * o + 4.f * y;
                part += uu * uu;
                y1[r] = y + f * dtv + hsdt * dW1[r];
                st2[r] = y1[r];
            }
            *(floatx4*)(out0 + obase + 16) = st2;
        }
        part += __shfl_xor(part, 16);
        part += __shfl_xor(part, 32);
        lq += 0.5f * part * dtv;
        if (quad == 0) traj[(size_t)(i + 1) * NPART + n] = lq;
    }
}

// out1[i] = logqp trajectory at flat (t*N+n) index 41*i + 40
__global__ void gather_logqp(const float* __restrict__ traj, float* __restrict__ out1) {
    int i = blockIdx.x * 256 + threadIdx.x;
    if (i < NPART) out1[i] = traj[(size_t)41 * i + 40];
}

extern "C" void kernel_launch(void* const* d_in, const int* in_sizes, int n_in,
                              void* d_out, int out_size, void* d_ws, size_t ws_size,
                              hipStream_t stream) {
    const float* z      = (const float*)d_in[0];
    const float* t_arr  = (const float*)d_in[1];
    const float* Tx     = (const float*)d_in[2];
    const float* noise  = (const float*)d_in[3];
    const float* tw_in  = (const float*)d_in[4];
    const float* tb_in  = (const float*)d_in[5];
    const float* tw_h   = (const float*)d_in[6];
    const float* tb_h   = (const float*)d_in[7];
    const float* tw_out = (const float*)d_in[8];
    const float* tb_out = (const float*)d_in[9];
    const float* dw_in  = (const float*)d_in[10];
    const float* db_in  = (const float*)d_in[11];
    const float* dw_h   = (const float*)d_in[12];
    const float* db_h   = (const float*)d_in[13];
    const float* dw_out = (const float*)d_in[14];
    const float* db_out = (const float*)d_in[15];

    float* wsf  = (float*)d_ws;
    float* traj = wsf + TRAJ_OFF;
    float* out0 = (float*)d_out;
    float* out1 = out0 + OUT0_ELEMS;

    hipLaunchKernelGGL(sde_mfma, dim3(256), dim3(256), 0, stream,
                       z, t_arr, Tx, noise, dw_in, db_in, dw_h, db_h,
                       dw_out, db_out, tw_in, tb_in, tw_h, tb_h, tw_out, tb_out,
                       out0, traj);
    hipLaunchKernelGGL(gather_logqp, dim3(64), dim3(256), 0, stream, traj, out1);
}

// Round 4
// 254.060 us; speedup vs baseline: 1.0976x; 1.0976x over previous
//
#include <hip/hip_runtime.h>
#include <math.h>
#include <stdint.h>

#define NPART 16384
#define NSTEP 40
#define DIMA  22
#define OUT0_ELEMS 13434880
#define TRAJ_OFF   160

typedef __attribute__((ext_vector_type(8))) short short8;
typedef __attribute__((ext_vector_type(4))) float floatx4;
typedef __attribute__((ext_vector_type(4))) int   intx4;
typedef __attribute__((ext_vector_type(2))) int   intx2;

union V4 { intx4 i; short8 s; floatx4 f; };

// ---- LDS map (bytes): permuted-weight image (staging only; hoisted to regs) ----
#define AIN_B   0
#define AH_B    5120
#define AOUT_B  56320
#define U_B     61440
#define LDS_BYTES 62080
#define STAGE_DW  15360

// In-loop activation-exchange regions: reuse [0, 24576) after weight hoist.
// Per pair: ACT buf0 (10 slots x 256B), ACT buf1, BIN (4 slots x 256B).
#define PAIR_STRIDE 6144
#define ACT1_OFF    2560
#define BIN_OFF     5120

// HW packed f32->bf16 (RNE), single instruction.
__device__ __forceinline__ uint32_t pk2(float a0, float a1) {
    uint32_t r;
    asm("v_cvt_pk_bf16_f32 %0, %1, %2" : "=v"(r) : "v"(a0), "v"(a1));
    return r;
}
__device__ __forceinline__ float fast_tanh(float x) {
    float e = __expf(2.0f * x);
    return 1.0f - 2.0f * __builtin_amdgcn_rcpf(e + 1.0f);
}
__device__ __forceinline__ void relupk(floatx4 a, uint32_t& d0, uint32_t& d1) {
    d0 = pk2(fmaxf(a[0], 0.f), fmaxf(a[1], 0.f));
    d1 = pk2(fmaxf(a[2], 0.f), fmaxf(a[3], 0.f));
}
__device__ __forceinline__ void tanhpk(floatx4 a, uint32_t& d0, uint32_t& d1) {
    d0 = pk2(fast_tanh(a[0]), fast_tanh(a[1]));
    d1 = pk2(fast_tanh(a[2]), fast_tanh(a[3]));
}
// LDS-only barrier: does NOT drain vmcnt (global stores keep flying).
// Cross-wave traffic here is purely LDS, so lgkmcnt(0) + s_barrier suffices.
__device__ __forceinline__ void pbar() {
    asm volatile("s_waitcnt lgkmcnt(0)" ::: "memory");
    __builtin_amdgcn_s_barrier();
    asm volatile("" ::: "memory");
}

__global__ __launch_bounds__(512, 2) void sde_mfma(
    const float* __restrict__ z,      const float* __restrict__ t_arr,
    const float* __restrict__ Tx,     const float* __restrict__ noise,
    const float* __restrict__ dw_in,  const float* __restrict__ db_in,
    const float* __restrict__ dw_h,   const float* __restrict__ db_h,
    const float* __restrict__ dw_out, const float* __restrict__ db_out,
    const float* __restrict__ tw_in,  const float* __restrict__ tb_in,
    const float* __restrict__ tw_h,   const float* __restrict__ tb_h,
    const float* __restrict__ tw_out, const float* __restrict__ tb_out,
    float* __restrict__ out0,         float* __restrict__ traj)
{
    __shared__ __align__(16) uint8_t lds[LDS_BYTES];
    const int tid = threadIdx.x;

    // ---- stage PERMUTED bf16 weight image global -> LDS ----
    //   A'[m][32kt+8q+2w+jj] = A[m][16(2kt+(w>>1)) + 4q + 2(w&1) + jj]
    // Input-layer bias folded at B-slot (q=2, w=2); B[k=20]=1.0 injected by
    // quad==2 lanes each step.
    for (int di = tid; di < STAGE_DW; di += 512) {
        uint32_t val = 0u;
        if (di < 1280) {                       // AIN: x = [y(20), u_t(4), bias@k20]
            int r = di & 255, lane = r >> 2, w = r & 3;
            int m = lane & 15, q = lane >> 4, mt = di >> 8;
            int f = -1;
            if (w < 2)            f = 4 * q + 2 * w;
            else if (q == 0)      f = 16 + 2 * (w - 2);
            else if (q == 1)      f = 20 + 2 * (w - 2);
            if (f >= 0)               val = pk2(dw_in[(mt * 16 + m) * 24 + f],
                                                dw_in[(mt * 16 + m) * 24 + f + 1]);
            else if (q == 2 && w == 2) val = pk2(db_in[mt * 16 + m], 0.f);
        } else if (di < 14080) {               // AH: 20 groups x 640 dw
            int q2 = di - 1280, g = q2 / 640, r = q2 % 640;
            int l = g / 5, mt = g % 5;
            int lane, f;
            if (r < 512) {
                int kt = r >> 8, rr = r & 255, w = rr & 3;
                lane = rr >> 2;
                f = 16 * (2 * kt + (w >> 1)) + 4 * (lane >> 4) + 2 * (w & 1);
            } else {
                int rr = r - 512, d = rr & 1;
                lane = rr >> 1;
                f = 64 + 4 * (lane >> 4) + 2 * d;
            }
            int m = lane & 15;
            val = pk2(dw_h[l * 6400 + (mt * 16 + m) * 80 + f],
                      dw_h[l * 6400 + (mt * 16 + m) * 80 + f + 1]);
        } else {                               // AOUT: 2 groups x 640 dw
            int q2 = di - 14080, mt = q2 / 640, r = q2 % 640;
            int lane, f;
            if (r < 512) {
                int kt = r >> 8, rr = r & 255, w = rr & 3;
                lane = rr >> 2;
                f = 16 * (2 * kt + (w >> 1)) + 4 * (lane >> 4) + 2 * (w & 1);
            } else {
                int rr = r - 512, d = rr & 1;
                lane = rr >> 1;
                f = 64 + 4 * (lane >> 4) + 2 * d;
            }
            int m = mt * 16 + (lane & 15);
            if (m < 20) val = pk2(dw_out[m * 80 + f], dw_out[m * 80 + f + 1]);
        }
        ((uint32_t*)lds)[di] = val;
    }
    if (tid < NSTEP) {   // t-MLP u(t_i), fp32
        float ti = t_arr[tid];
        float hh[20], h2[20];
        #pragma unroll
        for (int j = 0; j < 20; j++) {
            float v = tw_in[j] * ti + tb_in[j];
            hh[j] = v > 0.f ? v : 0.f;
        }
        #pragma unroll
        for (int l = 0; l < 4; l++) {
            #pragma unroll
            for (int j = 0; j < 20; j++) {
                float a = tb_h[l * 20 + j];
                #pragma unroll
                for (int k = 0; k < 20; k++) a += tw_h[(l * 20 + j) * 20 + k] * hh[k];
                h2[j] = a > 0.f ? a : 0.f;
            }
            #pragma unroll
            for (int j = 0; j < 20; j++) hh[j] = h2[j];
        }
        #pragma unroll
        for (int c = 0; c < 4; c++) {
            float a = tb_out[c];
            #pragma unroll
            for (int k = 0; k < 20; k++) a += tw_out[c * 20 + k] * hh[k];
            ((float*)(lds + U_B))[tid * 4 + c] = a;
        }
    }

    const int lane = tid & 63;
    const int n15  = lane & 15;
    const int quad = lane >> 4;
    const int wv   = tid >> 6;            // 0..7
    const int pairid = wv & 3;
    const bool roleB = (wv >= 4);         // pair (wv, wv+4) -> same SIMD
    const int n    = blockIdx.x * 64 + pairid * 16 + n15;
    const float Txb = Tx[blockIdx.x];
    const float dtv = t_arr[1] - t_arr[0];
    const float sdt = sqrtf(dtv);
    const float hsdt = 0.5f * sdt;

    uint8_t* const pb   = lds + pairid * PAIR_STRIDE;
    uint32_t* const act0 = (uint32_t*)pb + lane;                 // + slot*64
    uint32_t* const act1 = (uint32_t*)(pb + ACT1_OFF) + lane;
    uint32_t* const binp = (uint32_t*)(pb + BIN_OFF) + lane;

    __syncthreads();   // weight image + u-table staged

    // ---- hoist weights to registers, role-split; union layout:
    //  A: aIn[0..2]=in mt0-2; aH*[l*3+mt]=hidden mt0-2 (12 groups)
    //  B: aIn[0..1]=in mt3-4; aH*[l*2+mt]=hidden mt3-4 (8); aH*[8+mt]=out mt (2)
    V4 aIn[3], aH0[12], aH1[12], aH2[12];
    if (!roleB) {
        #pragma unroll
        for (int mt = 0; mt < 3; mt++)
            aIn[mt].i = *(const intx4*)(lds + AIN_B + mt * 1024 + lane * 16);
        #pragma unroll
        for (int l = 0; l < 4; l++) {
            #pragma unroll
            for (int mt = 0; mt < 3; mt++) {
                const uint8_t* grp = lds + AH_B + (size_t)(l * 5 + mt) * 2560;
                const int g = l * 3 + mt;
                aH0[g].i = *(const intx4*)(grp + lane * 16);
                aH1[g].i = *(const intx4*)(grp + 1024 + lane * 16);
                intx2 h2 = *(const intx2*)(grp + 2048 + lane * 8);
                uint32_t bd = (quad == 0) ? pk2(db_h[l * 80 + mt * 16 + n15], 0.f) : 0u;
                aH2[g].i = (intx4){h2[0], h2[1], (int)bd, 0};
            }
        }
    } else {
        #pragma unroll
        for (int mt = 0; mt < 2; mt++)
            aIn[mt].i = *(const intx4*)(lds + AIN_B + (3 + mt) * 1024 + lane * 16);
        #pragma unroll
        for (int l = 0; l < 4; l++) {
            #pragma unroll
            for (int mt = 0; mt < 2; mt++) {
                const uint8_t* grp = lds + AH_B + (size_t)(l * 5 + 3 + mt) * 2560;
                const int g = l * 2 + mt;
                aH0[g].i = *(const intx4*)(grp + lane * 16);
                aH1[g].i = *(const intx4*)(grp + 1024 + lane * 16);
                intx2 h2 = *(const intx2*)(grp + 2048 + lane * 8);
                uint32_t bd = (quad == 0) ? pk2(db_h[l * 80 + (3 + mt) * 16 + n15], 0.f) : 0u;
                aH2[g].i = (intx4){h2[0], h2[1], (int)bd, 0};
            }
        }
        #pragma unroll
        for (int mt = 0; mt < 2; mt++) {
            const uint8_t* grp = lds + AOUT_B + (size_t)mt * 2560;
            const int g = 8 + mt;
            aH0[g].i = *(const intx4*)(grp + lane * 16);
            aH1[g].i = *(const intx4*)(grp + 1024 + lane * 16);
            intx2 h2 = *(const intx2*)(grp + 2048 + lane * 8);
            int m = mt * 16 + n15;
            uint32_t bd = (quad == 0 && m < 20) ? pk2(db_out[m], 0.f) : 0u;
            aH2[g].i = (intx4){h2[0], h2[1], (int)bd, 0};
        }
    }

    // ---- B: init state + first outputs ----
    float y0[4] = {0.f, 0.f, 0.f, 0.f}, y1[4] = {0.f, 0.f, 0.f, 0.f};
    V4 binB; binB.i = (intx4){0, 0, 0, 0};
    float lq = 0.f;
    if (roleB) {
        floatx4 zv = *(const floatx4*)(z + (size_t)n * 20 + quad * 4);
        #pragma unroll
        for (int r = 0; r < 4; r++) y0[r] = zv[r];
        *(floatx4*)(out0 + (size_t)n * 20 + quad * 4) = zv;
        if (quad == 0) {
            floatx4 z2 = *(const floatx4*)(z + (size_t)n * 20 + 16);
            #pragma unroll
            for (int r = 0; r < 4; r++) y1[r] = z2[r];
            *(floatx4*)(out0 + (size_t)n * 20 + 16) = z2;
            traj[n] = 0.f;
        }
    }
    __syncthreads();   // all hoist reads done -> act/bin region reusable

    if (roleB) {       // build bin for step 0, publish to A
        const floatx4 uv0 = *(const floatx4*)((const float*)(lds + U_B));
        float ut0 = uv0[0] * Txb, ut1 = uv0[1] * Txb;
        float ut2 = uv0[2] * Txb, ut3 = uv0[3] * Txb;
        binB.i[0] = pk2(y0[0], y0[1]);
        binB.i[1] = pk2(y0[2], y0[3]);
        if (quad == 0)      { binB.i[2] = pk2(y1[0], y1[1]); binB.i[3] = pk2(y1[2], y1[3]); }
        else if (quad == 1) { binB.i[2] = pk2(ut0, ut1);     binB.i[3] = pk2(ut2, ut3); }
        else if (quad == 2) { binB.i[2] = 0x00003F80;        binB.i[3] = 0; }
        else                { binB.i[2] = 0;                 binB.i[3] = 0; }
        binp[0] = binB.i[0]; binp[64] = binB.i[1];
        binp[128] = binB.i[2]; binp[192] = binB.i[3];
    }
    __syncthreads();   // bin0 visible

    const floatx4 zf = {0.f, 0.f, 0.f, 0.f};
    floatx4 dW0 = zf, dW1 = zf, uvn = zf;
    uint32_t pka[2], pkb[2], pkc[2];

    for (int i = 0; i < NSTEP; i++) {
        if (roleB) {   // loads for this step; consumed ~2K cycles later at s5
            size_t nb = ((size_t)i * NPART + n) * DIMA;
            dW0 = *(const floatx4*)(noise + nb + quad * 4);
            if (quad == 0) dW1 = *(const floatx4*)(noise + nb + 16);
            int inx = (i + 1 < NSTEP) ? i + 1 : i;
            uvn = *(const floatx4*)((const float*)(lds + U_B) + inx * 4);
        }

        // ---- s0: input layer -> act buf0 ----
        if (!roleB) {
            V4 binA;
            binA.i = (intx4){(int)binp[0], (int)binp[64], (int)binp[128], (int)binp[192]};
            floatx4 a0 = __builtin_amdgcn_mfma_f32_16x16x32_bf16(aIn[0].s, binA.s, zf, 0, 0, 0);
            floatx4 a1 = __builtin_amdgcn_mfma_f32_16x16x32_bf16(aIn[1].s, binA.s, zf, 0, 0, 0);
            floatx4 a2 = __builtin_amdgcn_mfma_f32_16x16x32_bf16(aIn[2].s, binA.s, zf, 0, 0, 0);
            relupk(a0, pka[0], pka[1]);
            relupk(a1, pkb[0], pkb[1]);
            relupk(a2, pkc[0], pkc[1]);
            act0[0]   = pka[0]; act0[64]  = pka[1];
            act0[128] = pkb[0]; act0[192] = pkb[1];
            act0[256] = pkc[0]; act0[320] = pkc[1];
        } else {
            floatx4 a0 = __builtin_amdgcn_mfma_f32_16x16x32_bf16(aIn[0].s, binB.s, zf, 0, 0, 0);
            floatx4 a1 = __builtin_amdgcn_mfma_f32_16x16x32_bf16(aIn[1].s, binB.s, zf, 0, 0, 0);
            relupk(a0, pka[0], pka[1]);
            relupk(a1, pkb[0], pkb[1]);
            act0[384] = pka[0]; act0[448] = pka[1];
            act0[512] = pkb[0]; act0[576] = pkb[1];
        }
        pbar();

        // ---- s1..s4: hidden layers, ping-pong act buffers ----
        #pragma unroll
        for (int l = 0; l < 4; l++) {
            uint32_t* rb = (l & 1) ? act1 : act0;
            uint32_t* wb = (l & 1) ? act0 : act1;
            if (!roleB) {
                uint32_t r6 = rb[384], r7 = rb[448], r8 = rb[512], r9 = rb[576];
                V4 b0, b1, b2;
                b0.i = (intx4){(int)pka[0], (int)pka[1], (int)pkb[0], (int)pkb[1]};
                b1.i = (intx4){(int)pkc[0], (int)pkc[1], (int)r6, (int)r7};
                b2.i = (intx4){(int)r8, (int)r9, 0x00003F80, 0};
                floatx4 acc[3];
                #pragma unroll
                for (int mt = 0; mt < 3; mt++) {
                    const int g = l * 3 + mt;
                    floatx4 c = __builtin_amdgcn_mfma_f32_16x16x32_bf16(aH0[g].s, b0.s, zf, 0, 0, 0);
                    c = __builtin_amdgcn_mfma_f32_16x16x32_bf16(aH1[g].s, b1.s, c, 0, 0, 0);
                    acc[mt] = __builtin_amdgcn_mfma_f32_16x16x32_bf16(aH2[g].s, b2.s, c, 0, 0, 0);
                }
                tanhpk(acc[0], pka[0], pka[1]);
                tanhpk(acc[1], pkb[0], pkb[1]);
                tanhpk(acc[2], pkc[0], pkc[1]);
                wb[0]   = pka[0]; wb[64]  = pka[1];
                wb[128] = pkb[0]; wb[192] = pkb[1];
                wb[256] = pkc[0]; wb[320] = pkc[1];
            } else {
                uint32_t r0 = rb[0], r1 = rb[64], r2 = rb[128], r3 = rb[192], r4 = rb[256], r5 = rb[320];
                V4 b0, b1, b2;
                b0.i = (intx4){(int)r0, (int)r1, (int)r2, (int)r3};
                b1.i = (intx4){(int)r4, (int)r5, (int)pka[0], (int)pka[1]};
                b2.i = (intx4){(int)pkb[0], (int)pkb[1], 0x00003F80, 0};
                floatx4 acc[2];
                #pragma unroll
                for (int mt = 0; mt < 2; mt++) {
                    const int g = l * 2 + mt;
                    floatx4 c = __builtin_amdgcn_mfma_f32_16x16x32_bf16(aH0[g].s, b0.s, zf, 0, 0, 0);
                    c = __builtin_amdgcn_mfma_f32_16x16x32_bf16(aH1[g].s, b1.s, c, 0, 0, 0);
                    acc[mt] = __builtin_amdgcn_mfma_f32_16x16x32_bf16(aH2[g].s, b2.s, c, 0, 0, 0);
                }
                tanhpk(acc[0], pka[0], pka[1]);
                tanhpk(acc[1], pkb[0], pkb[1]);
                wb[384] = pka[0]; wb[448] = pka[1];
                wb[512] = pkb[0]; wb[576] = pkb[1];
            }
            pbar();
        }

        // ---- s5: output layer + SDE update + logqp (B only; A waits) ----
        if (roleB) {
            uint32_t r0 = act0[0], r1 = act0[64], r2 = act0[128], r3 = act0[192], r4 = act0[256], r5 = act0[320];
            V4 b0, b1, b2;
            b0.i = (intx4){(int)r0, (int)r1, (int)r2, (int)r3};
            b1.i = (intx4){(int)r4, (int)r5, (int)pka[0], (int)pka[1]};
            b2.i = (intx4){(int)pkb[0], (int)pkb[1], 0x00003F80, 0};
            floatx4 oacc[2];
            #pragma unroll
            for (int mt = 0; mt < 2; mt++) {
                const int g = 8 + mt;
                floatx4 c = __builtin_amdgcn_mfma_f32_16x16x32_bf16(aH0[g].s, b0.s, zf, 0, 0, 0);
                c = __builtin_amdgcn_mfma_f32_16x16x32_bf16(aH1[g].s, b1.s, c, 0, 0, 0);
                oacc[mt] = __builtin_amdgcn_mfma_f32_16x16x32_bf16(aH2[g].s, b2.s, c, 0, 0, 0);
            }

            float part = 0.f;
            size_t obase = ((size_t)(i + 1) * NPART + n) * 20;
            floatx4 st;
            #pragma unroll
            for (int r = 0; r < 4; r++) {
                float o = oacc[0][r];
                float y = y0[r];
                float f = o + y;                 // f = mlp - h, h = -y
                float uu = 2.f * o + 4.f * y;    // (f - h)/sigma
                part += uu * uu;
                y0[r] = y + f * dtv + hsdt * dW0[r];
                st[r] = y0[r];
            }
            *(floatx4*)(out0 + obase + quad * 4) = st;
            if (quad == 0) {
                floatx4 st2;
                #pragma unroll
                for (int r = 0; r < 4; r++) {
                    float o = oacc[1][r];
                    float y = y1[r];
                    float f = o + y;
                    float uu = 2.f * o + 4.f * y;
                    part += uu * uu;
                    y1[r] = y + f * dtv + hsdt * dW1[r];
                    st2[r] = y1[r];
                }
                *(floatx4*)(out0 + obase + 16) = st2;
            }
            part += __shfl_xor(part, 16);
            part += __shfl_xor(part, 32);
            lq += 0.5f * part * dtv;
            if (quad == 0) traj[(size_t)(i + 1) * NPART + n] = lq;

            // build bin for step i+1 (uses u(t_{i+1})), publish to A
            float ut0 = uvn[0] * Txb, ut1 = uvn[1] * Txb;
            float ut2 = uvn[2] * Txb, ut3 = uvn[3] * Txb;
            binB.i[0] = pk2(y0[0], y0[1]);
            binB.i[1] = pk2(y0[2], y0[3]);
            if (quad == 0)      { binB.i[2] = pk2(y1[0], y1[1]); binB.i[3] = pk2(y1[2], y1[3]); }
            else if (quad == 1) { binB.i[2] = pk2(ut0, ut1);     binB.i[3] = pk2(ut2, ut3); }
            else if (quad == 2) { binB.i[2] = 0x00003F80;        binB.i[3] = 0; }
            else                { binB.i[2] = 0;                 binB.i[3] = 0; }
            binp[0] = binB.i[0]; binp[64] = binB.i[1];
            binp[128] = binB.i[2]; binp[192] = binB.i[3];
        }
        pbar();
    }
}

// out1[i] = logqp trajectory at flat (t*N+n) index 41*i + 40
__global__ void gather_logqp(const float* __restrict__ traj, float* __restrict__ out1) {
    int i = blockIdx.x * 256 + threadIdx.x;
    if (i < NPART) out1[i] = traj[(size_t)41 * i + 40];
}

extern "C" void kernel_launch(void* const* d_in, const int* in_sizes, int n_in,
                              void* d_out, int out_size, void* d_ws, size_t ws_size,
                              hipStream_t stream) {
    const float* z      = (const float*)d_in[0];
    const float* t_arr  = (const float*)d_in[1];
    const float* Tx     = (const float*)d_in[2];
    const float* noise  = (const float*)d_in[3];
    const float* tw_in  = (const float*)d_in[4];
    const float* tb_in  = (const float*)d_in[5];
    const float* tw_h   = (const float*)d_in[6];
    const float* tb_h   = (const float*)d_in[7];
    const float* tw_out = (const float*)d_in[8];
    const float* tb_out = (const float*)d_in[9];
    const float* dw_in  = (const float*)d_in[10];
    const float* db_in  = (const float*)d_in[11];
    const float* dw_h   = (const float*)d_in[12];
    const float* db_h   = (const float*)d_in[13];
    const float* dw_out = (const float*)d_in[14];
    const float* db_out = (const float*)d_in[15];

    float* wsf  = (float*)d_ws;
    float* traj = wsf + TRAJ_OFF;
    float* out0 = (float*)d_out;
    float* out1 = out0 + OUT0_ELEMS;

    hipLaunchKernelGGL(sde_mfma, dim3(256), dim3(512), 0, stream,
                       z, t_arr, Tx, noise, dw_in, db_in, dw_h, db_h,
                       dw_out, db_out, tw_in, tb_in, tw_h, tb_h, tw_out, tb_out,
                       out0, traj);
    hipLaunchKernelGGL(gather_logqp, dim3(64), dim3(256), 0, stream, traj, out1);
}